// Round 2
// baseline (288.990 us; speedup 1.0000x reference)
//
#include <hip/hip_runtime.h>

// AdaptiveAttentionLoss: focal-weighted CE (C=2, beta=2) + segmented mean over
// G=4096 groups + mean over present groups.
// Memory-bound: 256 MiB mandatory read -> ~43us floor at 6.3 TB/s.

#define G_GROUPS 4096

__global__ void aal_zero_kernel(float* __restrict__ acc) {
    int i = blockIdx.x * blockDim.x + threadIdx.x;
    if (i < 2 * G_GROUPS) acc[i] = 0.0f;
}

// 32 KiB LDS/block; 512 thr = 8 waves/block; 2 blocks/CU -> 4 waves/SIMD.
__global__ __launch_bounds__(512, 4) void aal_accum_kernel(
    const float4* __restrict__ x,      // [N/2] float4 == 2 samples each
    const int4*  __restrict__ index,   // [N/4]
    const int4*  __restrict__ label,   // [N/4]
    float* __restrict__ gsum,          // [G]
    float* __restrict__ gcnt,          // [G]
    int nvec)                          // N/4
{
    __shared__ float    s_sum[G_GROUPS];
    __shared__ unsigned s_cnt[G_GROUPS];
    for (int i = threadIdx.x; i < G_GROUPS; i += blockDim.x) {
        s_sum[i] = 0.0f;
        s_cnt[i] = 0u;
    }
    __syncthreads();

    const int tid    = blockIdx.x * blockDim.x + threadIdx.x;
    const int stride = gridDim.x * blockDim.x;

    for (int v = tid; v < nvec; v += stride) {
        // 4 samples: 2x float4 (x pairs), 1x int4 index, 1x int4 label.
        float4 xa = x[2 * v];
        float4 xb = x[2 * v + 1];
        int4 idx = index[v];
        int4 lab = label[v];

        float x0[4] = {xa.x, xa.z, xb.x, xb.z};
        float x1[4] = {xa.y, xa.w, xb.y, xb.w};
        int   ii[4] = {idx.x, idx.y, idx.z, idx.w};
        int   ll[4] = {lab.x, lab.y, lab.z, lab.w};

#pragma unroll
        for (int s = 0; s < 4; ++s) {  // static indexing only (rule #20)
            float xt = ll[s] ? x1[s] : x0[s];
            float xo = ll[s] ? x0[s] : x1[s];
            float d  = xo - xt;
            // ce = logsumexp(x) - x_true = softplus(d), numerically stable
            float ce = fmaxf(d, 0.0f) + log1pf(expf(-fabsf(d)));
            float p  = expf(-ce);            // softmax prob of true class
            float w  = 1.0f - p * p;         // 1 - p^beta, beta=2
            float val = w * ce;
            atomicAdd(&s_sum[ii[s]], val);
            atomicAdd(&s_cnt[ii[s]], 1u);
        }
    }
    __syncthreads();

    // One global atomic pair per present group per block (G12).
    for (int i = threadIdx.x; i < G_GROUPS; i += blockDim.x) {
        unsigned c = s_cnt[i];
        if (c) {
            atomicAdd(&gsum[i], s_sum[i]);
            atomicAdd(&gcnt[i], (float)c);   // exact: counts <= 2^24
        }
    }
}

__global__ __launch_bounds__(1024) void aal_finalize_kernel(
    const float* __restrict__ gsum,
    const float* __restrict__ gcnt,
    float* __restrict__ out)
{
    __shared__ float s_mean[1024];
    __shared__ float s_pres[1024];
    const int t = threadIdx.x;
    float msum = 0.0f, pres = 0.0f;
    for (int i = t; i < G_GROUPS; i += 1024) {
        float c = gcnt[i];
        if (c > 0.0f) {
            msum += gsum[i] / c;
            pres += 1.0f;
        }
    }
    s_mean[t] = msum;
    s_pres[t] = pres;
    __syncthreads();
    for (int o = 512; o > 0; o >>= 1) {
        if (t < o) {
            s_mean[t] += s_mean[t + o];
            s_pres[t] += s_pres[t + o];
        }
        __syncthreads();
    }
    if (t == 0) out[0] = s_mean[0] / s_pres[0];
}

extern "C" void kernel_launch(void* const* d_in, const int* in_sizes, int n_in,
                              void* d_out, int out_size, void* d_ws, size_t ws_size,
                              hipStream_t stream) {
    const float4* x     = (const float4*)d_in[0];
    const int4*   index = (const int4*)d_in[1];
    const int4*   label = (const int4*)d_in[2];
    const int N = in_sizes[1];          // index element count == N samples
    const int nvec = N / 4;             // N = 2^24, divisible by 4

    float* gsum = (float*)d_ws;         // [G]
    float* gcnt = gsum + G_GROUPS;      // [G]
    float* out  = (float*)d_out;

    aal_zero_kernel<<<(2 * G_GROUPS + 255) / 256, 256, 0, stream>>>(gsum);
    aal_accum_kernel<<<512, 512, 0, stream>>>(x, index, label, gsum, gcnt, nvec);
    aal_finalize_kernel<<<1, 1024, 0, stream>>>(gsum, gcnt, out);
}